// Round 1
// baseline (677.114 us; speedup 1.0000x reference)
//
#include <hip/hip_runtime.h>
#include <hip/hip_bf16.h>
#include <cmath>

#define V_SIZE 50000
#define B_SIZE 256
#define D_SIZE 64
#define NCTX 8          // 2N context rows
#define NROWS (NCTX * B_SIZE)   // 2048 one-hot rows

// ---------------------------------------------------------------------------
// K1: extract one-hot indices. One block per (i,b) row; 409.6 MB streamed,
// float4-coalesced. Exactly one element per row is 1.0f.
// ---------------------------------------------------------------------------
__global__ __launch_bounds__(256) void k_find_ids(const float* __restrict__ in,
                                                  int* __restrict__ ids) {
    const int row = blockIdx.x;  // [0, 2048)
    const float4* r4 = (const float4*)(in + (size_t)row * V_SIZE);
    for (int j = threadIdx.x; j < V_SIZE / 4; j += 256) {
        float4 x = r4[j];
        if (x.x > 0.5f) ids[row] = 4 * j;
        if (x.y > 0.5f) ids[row] = 4 * j + 1;
        if (x.z > 0.5f) ids[row] = 4 * j + 2;
        if (x.w > 0.5f) ids[row] = 4 * j + 3;
    }
}

// ---------------------------------------------------------------------------
// K2: h[b][d] = b1[d] + (1/8) * sum_i w1[d*V + ids[i,b]].
// One block per b (64 threads = 1 wave, thread = d). Gather of 2048 cols.
// ---------------------------------------------------------------------------
__global__ __launch_bounds__(64) void k_h(const int* __restrict__ ids,
                                          const float* __restrict__ w1,
                                          const float* __restrict__ b1,
                                          float* __restrict__ h) {
    const int b = blockIdx.x;
    const int d = threadIdx.x;
    float acc = 0.0f;
#pragma unroll
    for (int i = 0; i < NCTX; ++i) {
        int id = ids[i * B_SIZE + b];          // wave-uniform -> scalar load
        acc += w1[(size_t)d * V_SIZE + id];
    }
    h[b * D_SIZE + d] = acc * 0.125f + b1[d];
}

// ---------------------------------------------------------------------------
// K3: logits[b][v] = dot(h[b,:], w2[v,:]) + b2[v].
// Thread owns one v; w2 row (64 floats) lives in VGPRs; h[b,:] addresses are
// wave-uniform -> scalar s_load path, broadcast for free. grid.y splits b.
// Writes are dword-coalesced along v.
// ---------------------------------------------------------------------------
__global__ __launch_bounds__(256) void k_logits(const float* __restrict__ h,
                                                const float* __restrict__ w2,
                                                const float* __restrict__ b2,
                                                float* __restrict__ out) {
    const int v = blockIdx.x * 256 + threadIdx.x;
    if (v >= V_SIZE) return;

    float4 w2r[16];
    const float4* wrow = (const float4*)(w2 + (size_t)v * D_SIZE);
#pragma unroll
    for (int j = 0; j < 16; ++j) w2r[j] = wrow[j];
    const float bias = b2[v];

    const int b0 = blockIdx.y * 64;
    for (int bi = 0; bi < 64; ++bi) {
        const int b = b0 + bi;
        const float4* hb = (const float4*)(h + b * D_SIZE);  // uniform addr
        float a0 = 0.f, a1 = 0.f, a2 = 0.f, a3 = 0.f;
#pragma unroll
        for (int j = 0; j < 16; j += 4) {
            float4 h0 = hb[j], h1 = hb[j + 1], h2 = hb[j + 2], h3 = hb[j + 3];
            a0 += w2r[j].x * h0.x + w2r[j].y * h0.y + w2r[j].z * h0.z + w2r[j].w * h0.w;
            a1 += w2r[j + 1].x * h1.x + w2r[j + 1].y * h1.y + w2r[j + 1].z * h1.z + w2r[j + 1].w * h1.w;
            a2 += w2r[j + 2].x * h2.x + w2r[j + 2].y * h2.y + w2r[j + 2].z * h2.z + w2r[j + 2].w * h2.w;
            a3 += w2r[j + 3].x * h3.x + w2r[j + 3].y * h3.y + w2r[j + 3].z * h3.z + w2r[j + 3].w * h3.w;
        }
        out[(size_t)b * V_SIZE + v] = (a0 + a1) + (a2 + a3) + bias;
    }
}

// ---------------------------------------------------------------------------
// K4: in-place log_softmax per row. One block per b. Online max/logsumexp
// (single read pass) -> block reduce -> rewrite pass.
// ---------------------------------------------------------------------------
__global__ __launch_bounds__(256) void k_logsoftmax(float* __restrict__ out) {
    const int b = blockIdx.x;
    float4* r4 = (float4*)(out + (size_t)b * V_SIZE);
    const int n4 = V_SIZE / 4;  // 12500

    float m = -1e30f, s = 0.0f;
    for (int j = threadIdx.x; j < n4; j += 256) {
        float4 x = r4[j];
        float mx = fmaxf(fmaxf(x.x, x.y), fmaxf(x.z, x.w));
        if (mx > m) { s *= __expf(m - mx); m = mx; }
        s += __expf(x.x - m) + __expf(x.y - m) + __expf(x.z - m) + __expf(x.w - m);
    }
    // wave (64-lane) butterfly reduce of (m, s)
    for (int off = 1; off < 64; off <<= 1) {
        float mo = __shfl_xor(m, off, 64);
        float so = __shfl_xor(s, off, 64);
        float M = fmaxf(m, mo);
        s = s * __expf(m - M) + so * __expf(mo - M);
        m = M;
    }
    __shared__ float sm[4], ss[4], slz[1];
    const int wid = threadIdx.x >> 6, lane = threadIdx.x & 63;
    if (lane == 0) { sm[wid] = m; ss[wid] = s; }
    __syncthreads();
    if (threadIdx.x == 0) {
        float M = sm[0], S = ss[0];
#pragma unroll
        for (int w = 1; w < 4; ++w) {
            float M2 = fmaxf(M, sm[w]);
            S = S * __expf(M - M2) + ss[w] * __expf(sm[w] - M2);
            M = M2;
        }
        slz[0] = M + __logf(S);
    }
    __syncthreads();
    const float logZ = slz[0];
    for (int j = threadIdx.x; j < n4; j += 256) {
        float4 x = r4[j];
        x.x -= logZ; x.y -= logZ; x.z -= logZ; x.w -= logZ;
        r4[j] = x;
    }
}

// ---------------------------------------------------------------------------
extern "C" void kernel_launch(void* const* d_in, const int* in_sizes, int n_in,
                              void* d_out, int out_size, void* d_ws, size_t ws_size,
                              hipStream_t stream) {
    const float* in = (const float*)d_in[0];   // [8, 256, 50000] one-hot
    const float* w1 = (const float*)d_in[1];   // [64, 50000]
    const float* b1 = (const float*)d_in[2];   // [64]
    const float* w2 = (const float*)d_in[3];   // [50000, 64]
    const float* b2 = (const float*)d_in[4];   // [50000]
    float* out = (float*)d_out;                // [256, 50000]

    int* ids = (int*)d_ws;                               // 2048 ints (8 KB)
    float* h = (float*)((char*)d_ws + 8192);             // 256*64 floats (64 KB)

    k_find_ids<<<NROWS, 256, 0, stream>>>(in, ids);
    k_h<<<B_SIZE, 64, 0, stream>>>(ids, w1, b1, h);
    k_logits<<<dim3((V_SIZE + 255) / 256, 4), 256, 0, stream>>>(h, w2, b2, out);
    k_logsoftmax<<<B_SIZE, 256, 0, stream>>>(out);
}

// Round 2
// 670.159 us; speedup vs baseline: 1.0104x; 1.0104x over previous
//
#include <hip/hip_runtime.h>
#include <hip/hip_bf16.h>
#include <cmath>

#define V_SIZE 50000
#define B_SIZE 256
#define D_SIZE 64
#define NCTX 8                  // 2N context rows
#define NROWS (NCTX * B_SIZE)   // 2048 one-hot rows
#define NCHUNK 4                // softmax row chunks
#define CHUNK4 3125             // float4s per chunk (50000/4/4)

// ---------------------------------------------------------------------------
// K1: extract one-hot indices. One block per (i,b) row; 409.6 MB streamed,
// float4-coalesced. Exactly one element per row is 1.0f. HBM-bound floor.
// ---------------------------------------------------------------------------
__global__ __launch_bounds__(256) void k_find_ids(const float* __restrict__ in,
                                                  int* __restrict__ ids) {
    const int row = blockIdx.x;  // [0, 2048)
    const float4* r4 = (const float4*)(in + (size_t)row * V_SIZE);
    for (int j = threadIdx.x; j < V_SIZE / 4; j += 256) {
        float4 x = r4[j];
        if (x.x > 0.5f) ids[row] = 4 * j;
        if (x.y > 0.5f) ids[row] = 4 * j + 1;
        if (x.z > 0.5f) ids[row] = 4 * j + 2;
        if (x.w > 0.5f) ids[row] = 4 * j + 3;
    }
}

// ---------------------------------------------------------------------------
// K2: h[b][d] = b1[d] + (1/8) * sum_i w1[d*V + ids[i,b]].
// One block per b (1 wave, thread = d). 2048-column gather, ~8.4 MB of lines.
// ---------------------------------------------------------------------------
__global__ __launch_bounds__(64) void k_h(const int* __restrict__ ids,
                                          const float* __restrict__ w1,
                                          const float* __restrict__ b1,
                                          float* __restrict__ h) {
    const int b = blockIdx.x;
    const int d = threadIdx.x;
    float acc = 0.0f;
#pragma unroll
    for (int i = 0; i < NCTX; ++i) {
        int id = ids[i * B_SIZE + b];          // wave-uniform -> scalar load
        acc += w1[(size_t)d * V_SIZE + id];
    }
    h[b * D_SIZE + d] = acc * 0.125f + b1[d];
}

// ---------------------------------------------------------------------------
// K3: logits[b][v] = dot(h[b,:], w2[v,:]) + b2[v].
// Thread owns one v; w2 row (64 floats) in VGPRs; h broadcast via uniform
// address (single L1 line per wave). grid.y splits b for occupancy.
// ---------------------------------------------------------------------------
__global__ __launch_bounds__(256) void k_logits(const float* __restrict__ h,
                                                const float* __restrict__ w2,
                                                const float* __restrict__ b2,
                                                float* __restrict__ out) {
    const int v = blockIdx.x * 256 + threadIdx.x;
    if (v >= V_SIZE) return;

    float4 w2r[16];
    const float4* wrow = (const float4*)(w2 + (size_t)v * D_SIZE);
#pragma unroll
    for (int j = 0; j < 16; ++j) w2r[j] = wrow[j];
    const float bias = b2[v];

    const int b0 = blockIdx.y * 64;
    for (int bi = 0; bi < 64; ++bi) {
        const int b = b0 + bi;
        const float4* hb = (const float4*)(h + b * D_SIZE);  // uniform addr
        float a0 = 0.f, a1 = 0.f, a2 = 0.f, a3 = 0.f;
#pragma unroll
        for (int j = 0; j < 16; j += 4) {
            float4 h0 = hb[j], h1 = hb[j + 1], h2 = hb[j + 2], h3 = hb[j + 3];
            a0 += w2r[j].x * h0.x + w2r[j].y * h0.y + w2r[j].z * h0.z + w2r[j].w * h0.w;
            a1 += w2r[j + 1].x * h1.x + w2r[j + 1].y * h1.y + w2r[j + 1].z * h1.z + w2r[j + 1].w * h1.w;
            a2 += w2r[j + 2].x * h2.x + w2r[j + 2].y * h2.y + w2r[j + 2].z * h2.z + w2r[j + 2].w * h2.w;
            a3 += w2r[j + 3].x * h3.x + w2r[j + 3].y * h3.y + w2r[j + 3].z * h3.z + w2r[j + 3].w * h3.w;
        }
        out[(size_t)b * V_SIZE + v] = (a0 + a1) + (a2 + a3) + bias;
    }
}

// ---------------------------------------------------------------------------
// K4a: per-(b, chunk) partial online max/logsumexp. grid (256 b, 4 chunks)
// = 1024 blocks -> 4x the occupancy of the old single-block-per-row pass.
// ---------------------------------------------------------------------------
__global__ __launch_bounds__(256) void k_stats(const float* __restrict__ out,
                                               float2* __restrict__ partial) {
    const int b = blockIdx.x, c = blockIdx.y;
    const float4* r4 = (const float4*)(out + (size_t)b * V_SIZE) + c * CHUNK4;

    float m = -1e30f, s = 0.0f;
    for (int j = threadIdx.x; j < CHUNK4; j += 256) {
        float4 x = r4[j];
        float mx = fmaxf(fmaxf(x.x, x.y), fmaxf(x.z, x.w));
        if (mx > m) { s *= __expf(m - mx); m = mx; }
        s += __expf(x.x - m) + __expf(x.y - m) + __expf(x.z - m) + __expf(x.w - m);
    }
    // 64-lane butterfly merge
    for (int off = 1; off < 64; off <<= 1) {
        float mo = __shfl_xor(m, off, 64);
        float so = __shfl_xor(s, off, 64);
        float M = fmaxf(m, mo);
        s = s * __expf(m - M) + so * __expf(mo - M);
        m = M;
    }
    __shared__ float sm[4], ss[4];
    const int wid = threadIdx.x >> 6, lane = threadIdx.x & 63;
    if (lane == 0) { sm[wid] = m; ss[wid] = s; }
    __syncthreads();
    if (threadIdx.x == 0) {
        float M = sm[0], S = ss[0];
#pragma unroll
        for (int w = 1; w < 4; ++w) {
            float M2 = fmaxf(M, sm[w]);
            S = S * __expf(M - M2) + ss[w] * __expf(sm[w] - M2);
            M = M2;
        }
        partial[b * NCHUNK + c] = make_float2(M, S);
    }
}

// ---------------------------------------------------------------------------
// K4b: merge 4 partials per row -> logZ[b]. One block, thread = b.
// ---------------------------------------------------------------------------
__global__ __launch_bounds__(256) void k_combine(const float2* __restrict__ partial,
                                                 float* __restrict__ logZ) {
    const int b = threadIdx.x;
    float2 p = partial[b * NCHUNK];
    float M = p.x, S = p.y;
#pragma unroll
    for (int c = 1; c < NCHUNK; ++c) {
        float2 q = partial[b * NCHUNK + c];
        float M2 = fmaxf(M, q.x);
        S = S * __expf(M - M2) + q.y * __expf(q.x - M2);
        M = M2;
    }
    logZ[b] = M + __logf(S);
}

// ---------------------------------------------------------------------------
// K4c: out[b][v] -= logZ[b]. grid (256 b, 4 chunks), float4 RMW.
// ---------------------------------------------------------------------------
__global__ __launch_bounds__(256) void k_apply(float* __restrict__ out,
                                               const float* __restrict__ logZ) {
    const int b = blockIdx.x, c = blockIdx.y;
    float4* r4 = (float4*)(out + (size_t)b * V_SIZE) + c * CHUNK4;
    const float lz = logZ[b];   // wave-uniform -> scalar load
    for (int j = threadIdx.x; j < CHUNK4; j += 256) {
        float4 x = r4[j];
        x.x -= lz; x.y -= lz; x.z -= lz; x.w -= lz;
        r4[j] = x;
    }
}

// ---------------------------------------------------------------------------
extern "C" void kernel_launch(void* const* d_in, const int* in_sizes, int n_in,
                              void* d_out, int out_size, void* d_ws, size_t ws_size,
                              hipStream_t stream) {
    const float* in = (const float*)d_in[0];   // [8, 256, 50000] one-hot
    const float* w1 = (const float*)d_in[1];   // [64, 50000]
    const float* b1 = (const float*)d_in[2];   // [64]
    const float* w2 = (const float*)d_in[3];   // [50000, 64]
    const float* b2 = (const float*)d_in[4];   // [50000]
    float* out = (float*)d_out;                // [256, 50000]

    char* ws = (char*)d_ws;
    int*    ids     = (int*)ws;                          // 8 KB
    float*  h       = (float*)(ws + 8192);               // 64 KB
    float2* partial = (float2*)(ws + 8192 + 65536);      // 8 KB
    float*  logZ    = (float*)(ws + 8192 + 65536 + 8192);// 1 KB

    k_find_ids<<<NROWS, 256, 0, stream>>>(in, ids);
    k_h<<<B_SIZE, 64, 0, stream>>>(ids, w1, b1, h);
    k_logits<<<dim3((V_SIZE + 255) / 256, 4), 256, 0, stream>>>(h, w2, b2, out);
    k_stats<<<dim3(B_SIZE, NCHUNK), 256, 0, stream>>>(out, partial);
    k_combine<<<1, 256, 0, stream>>>(partial, logZ);
    k_apply<<<dim3(B_SIZE, NCHUNK), 256, 0, stream>>>(out, logZ);
}